// Round 7
// baseline (355.608 us; speedup 1.0000x reference)
//
#include <hip/hip_runtime.h>
#include <hip/hip_bf16.h>

typedef __attribute__((ext_vector_type(8))) short short8;
typedef __attribute__((ext_vector_type(4))) float f32x4;
typedef unsigned int u32;

constexpr int N = 1024, M = 1024, D = 64, BH = 128;
constexpr size_t ATTN_ELEMS = (size_t)BH * N * M;     // 134217728
constexpr size_t QKV_ELEMS  = (size_t)BH * N * D;     // 8388608
constexpr int PB_BLOCKS = 2048;
constexpr int KCONV_BLOCKS = 512;
constexpr int COPY_BLOCKS_PER = 256;                   // per q/k/v tensor
constexpr int BR = 32, BC = 256;                       // per-iter rows x block cols

__device__ __forceinline__ short f2b(float x) {
    __hip_bfloat16 h = __float2bfloat16(x);
    return *reinterpret_cast<short*>(&h);
}

__device__ __forceinline__ void gl_lds16(const void* g, void* l) {
    __builtin_amdgcn_global_load_lds(
        (const __attribute__((address_space(1))) u32*)g,
        (__attribute__((address_space(3))) u32*)l, 16, 0, 0);
}

// Fused prep (unchanged from r6 — measured fine):
//   [0, PB_BLOCKS)            : pb[n,m] = pos_enc[n,m,:].w + b
//   [.., +KCONV_BLOCKS)       : keys fp32 -> bf16, PRE-SWIZZLED slot order
//                               kbf[b][r][qs] = bf16(keys[b][r][(qs ^ (r&7))*8 ..])
//   [.., +ncopy)              : q/k/v pass-through copies
//   last                      : scale = sum(w)/sqrt(16)
__global__ void prep_kernel(const float* __restrict__ q, const float* __restrict__ k,
                            const float* __restrict__ v, const float* __restrict__ pos,
                            const float* __restrict__ w, const float* __restrict__ b,
                            float* __restrict__ pb, short* __restrict__ kbf,
                            float* __restrict__ scale_p,
                            float* __restrict__ qout, float* __restrict__ kout,
                            float* __restrict__ vout, int ncopy) {
    const int bid = blockIdx.x, tid = threadIdx.x;
    if (bid < PB_BLOCKS) {
        const int lane16 = tid & 15;
        const f32x4 w4 = ((const f32x4*)w)[lane16];
        const float bias = b[0];
        const int group = (bid * 256 + tid) >> 4;
        const int ngroups = (PB_BLOCKS * 256) >> 4;
        for (int pair = group; pair < N * M; pair += ngroups) {
            f32x4 p = __builtin_nontemporal_load((const f32x4*)pos + (size_t)pair * 16 + lane16);
            float s = p[0]*w4[0] + p[1]*w4[1] + p[2]*w4[2] + p[3]*w4[3];
            s += __shfl_xor(s, 1);
            s += __shfl_xor(s, 2);
            s += __shfl_xor(s, 4);
            s += __shfl_xor(s, 8);
            if (lane16 == 0) pb[pair] = s + bias;
        }
    } else if (bid < PB_BLOCKS + KCONV_BLOCKS) {
        const int cid = bid - PB_BLOCKS;
        const int total_slots = BH * N * 8;        // 16B slots, 1048576
        for (int gs = cid * 256 + tid; gs < total_slots; gs += KCONV_BLOCKS * 256) {
            const int qs = gs & 7, gr = (gs >> 3) & (N - 1), bb = gs >> 13;
            const float* src = k + ((size_t)bb * N + gr) * D + (qs ^ (gr & 7)) * 8;
            f32x4 x0 = ((const f32x4*)src)[0], x1 = ((const f32x4*)src)[1];
            short8 pk;
#pragma unroll
            for (int e = 0; e < 4; e++) { pk[e] = f2b(x0[e]); pk[4 + e] = f2b(x1[e]); }
            *(short8*)&kbf[(size_t)gs * 8] = pk;
        }
    } else if (bid < PB_BLOCKS + KCONV_BLOCKS + ncopy) {
        const int cid = bid - PB_BLOCKS - KCONV_BLOCKS;
        const int which = cid >> 8, lid = cid & 255;
        const f32x4* __restrict__ src = (which == 0) ? (const f32x4*)q
                                      : (which == 1) ? (const f32x4*)k : (const f32x4*)v;
        f32x4* __restrict__ dst = (which == 0) ? (f32x4*)qout
                                : (which == 1) ? (f32x4*)kout : (f32x4*)vout;
        const int nel4 = (int)(QKV_ELEMS / 4);
        for (int i = lid * 256 + tid; i < nel4; i += COPY_BLOCKS_PER * 256) {
            f32x4 x = __builtin_nontemporal_load(src + i);
            __builtin_nontemporal_store(x, dst + i);
        }
    } else {
        if (tid < 64) {
            float val = w[tid];
#pragma unroll
            for (int o = 32; o > 0; o >>= 1) val += __shfl_down(val, o);
            if (tid == 0) scale_p[0] = val * 0.25f;
        }
    }
}

// attn = (K K^T)*scale + pb.  Block = (tc, batch): B-tile (256 rows) staged
// ONCE and hoisted into 16 register fragments; loop over tr stages only a 4KB
// A-tile (double-buffered, 1 gl_lds/thread/iter, overlapped with MFMA+stores).
// One barrier per iteration.  4 waves (2x2): 16 rows x 128 cols each.
__launch_bounds__(256)
__global__ void attn_kernel(const short* __restrict__ kbf, const float* __restrict__ pb,
                            const float* __restrict__ scale_p, float* __restrict__ out) {
    __shared__ short lB[BC * 64];                 // 32KB
    __shared__ short lA[2][BR * 64];              // 2 x 4KB
    const int tc = blockIdx.x & 3;
    const int batch = blockIdx.x >> 2;
    const int tid = threadIdx.x;
    const float scale = scale_p[0];
    const short* __restrict__ Kb = kbf + (size_t)batch * N * 64;

    const int lane = tid & 63, wv = tid >> 6;     // 4 waves
    const int wr = wv >> 1, wc = wv & 1;          // 2x2: 16 rows x 128 cols
    const int frow = lane & 15;
    const int kslot = lane >> 4;

    // Prologue: stage B rows [tc*256,+256) (2048 slots) and A for tr=0.
#pragma unroll
    for (int it = 0; it < 8; ++it) {
        const int slot = it * 256 + tid;
        const int row = slot >> 3, qs = slot & 7;
        gl_lds16(Kb + (size_t)(tc * BC + row) * 64 + qs * 8, &lB[slot * 8]);
    }
    {
        const int row = tid >> 3, qs = tid & 7;
        gl_lds16(Kb + (size_t)row * 64 + qs * 8, &lA[0][tid * 8]);
    }
    __syncthreads();

    // Hoist all 16 B fragments into registers (constant across tr).
    short8 bfrag[2][8];
#pragma unroll
    for (int h = 0; h < 2; ++h)
#pragma unroll
        for (int j = 0; j < 8; ++j) {
            const int rb = wc * 128 + j * 16 + frow;
            bfrag[h][j] = *(const short8*)&lB[rb * 64 + ((h * 4 + kslot) ^ (rb & 7)) * 8];
        }

    const int ocol = tc * BC + wc * 128 + (lane & 15);      // + j*16
    const size_t obase = (size_t)batch * N * M;

    for (int tr = 0; tr < 32; ++tr) {
        const int cur = tr & 1;
        if (tr) __syncthreads();                  // A[cur] loaded; A[cur^1] free
        if (tr + 1 < 32) {                        // issue next A stage early
            const int row = tid >> 3, qs = tid & 7;
            gl_lds16(Kb + (size_t)((tr + 1) * BR + row) * 64 + qs * 8,
                     &lA[cur ^ 1][tid * 8]);
        }

        const int ra = wr * 16 + frow;
        short8 a0 = *(const short8*)&lA[cur][ra * 64 + ((kslot)     ^ (ra & 7)) * 8];
        short8 a1 = *(const short8*)&lA[cur][ra * 64 + ((4 + kslot) ^ (ra & 7)) * 8];

        f32x4 acc[8] = {};
#pragma unroll
        for (int j = 0; j < 8; ++j)
            acc[j] = __builtin_amdgcn_mfma_f32_16x16x32_bf16(a0, bfrag[0][j], acc[j], 0, 0, 0);
#pragma unroll
        for (int j = 0; j < 8; ++j)
            acc[j] = __builtin_amdgcn_mfma_f32_16x16x32_bf16(a1, bfrag[1][j], acc[j], 0, 0, 0);

        const int orow = tr * BR + wr * 16 + (lane >> 4) * 4;
#pragma unroll
        for (int j = 0; j < 8; ++j)
#pragma unroll
            for (int r = 0; r < 4; ++r) {
                const size_t off = (size_t)(orow + r) * M + (ocol + j * 16);
                out[obase + off] = acc[j][r] * scale + pb[off];
            }
    }
}

extern "C" void kernel_launch(void* const* d_in, const int* in_sizes, int n_in,
                              void* d_out, int out_size, void* d_ws, size_t ws_size,
                              hipStream_t stream) {
    const float* queries = (const float*)d_in[0];
    const float* keys    = (const float*)d_in[1];
    const float* values  = (const float*)d_in[2];
    const float* pos_enc = (const float*)d_in[3];
    const float* w_pos   = (const float*)d_in[4];
    const float* b_pos   = (const float*)d_in[5];

    float* out  = (float*)d_out;
    float* qout = out + ATTN_ELEMS;
    float* kout = qout + QKV_ELEMS;
    float* vout = kout + QKV_ELEMS;

    // ws layout: pb (N*M floats) | scale (16 floats) | kbf (BH*N*64 shorts)
    const size_t need_ws = ((size_t)N * M + 16) * sizeof(float)
                         + (size_t)BH * N * 64 * sizeof(short);
    const int nblocks = (M / BC) * BH;            // 4 * 128 = 512

    if (ws_size >= need_ws) {
        float* pb      = (float*)d_ws;
        float* scale_p = pb + (size_t)N * M;
        short* kbf     = (short*)(scale_p + 16);
        const int ncopy = 3 * COPY_BLOCKS_PER;
        prep_kernel<<<dim3(PB_BLOCKS + KCONV_BLOCKS + ncopy + 1), dim3(256), 0, stream>>>(
            queries, keys, values, pos_enc, w_pos, b_pos, pb, kbf, scale_p,
            qout, kout, vout, ncopy);
        attn_kernel<<<dim3(nblocks), dim3(256), 0, stream>>>(kbf, pb, scale_p, out);
    } else {
        // Fallback: stash pb + scale + kbf in the q/k region of d_out (20MB),
        // run prep without copies, attn, then copy q/k/v after.
        float* pb      = qout;
        float* scale_p = pb + (size_t)N * M;
        short* kbf     = (short*)(scale_p + 16);
        prep_kernel<<<dim3(PB_BLOCKS + KCONV_BLOCKS + 1), dim3(256), 0, stream>>>(
            queries, keys, values, pos_enc, w_pos, b_pos, pb, kbf, scale_p,
            qout, kout, vout, /*ncopy=*/0);
        attn_kernel<<<dim3(nblocks), dim3(256), 0, stream>>>(kbf, pb, scale_p, out);
        hipMemcpyAsync(qout, queries, QKV_ELEMS * sizeof(float), hipMemcpyDeviceToDevice, stream);
        hipMemcpyAsync(kout, keys,    QKV_ELEMS * sizeof(float), hipMemcpyDeviceToDevice, stream);
        hipMemcpyAsync(vout, values,  QKV_ELEMS * sizeof(float), hipMemcpyDeviceToDevice, stream);
    }
}

// Round 9
// 211.609 us; speedup vs baseline: 1.6805x; 1.6805x over previous
//
#include <hip/hip_runtime.h>
#include <hip/hip_bf16.h>

typedef __attribute__((ext_vector_type(8))) short short8;
typedef __attribute__((ext_vector_type(4))) float f32x4;
typedef unsigned int u32;

constexpr int N = 1024, M = 1024, D = 64, BH = 128;
constexpr size_t ATTN_ELEMS = (size_t)BH * N * M;     // 134217728
constexpr size_t QKV_ELEMS  = (size_t)BH * N * D;     // 8388608
constexpr int PB_BLOCKS = 2048;
constexpr int KCONV_BLOCKS = 512;
constexpr int COPY_BLOCKS_PER = 256;                   // per q/k/v tensor
constexpr int BGROUP = 8;                              // batches per attn block
constexpr int BR = 32, BC = 256;                       // attn tile: 32 rows x 256 cols

__device__ __forceinline__ short f2b(float x) {
    __hip_bfloat16 h = __float2bfloat16(x);
    return *reinterpret_cast<short*>(&h);
}

__device__ __forceinline__ void gl_lds16(const void* g, void* l) {
    __builtin_amdgcn_global_load_lds(
        (const __attribute__((address_space(1))) u32*)g,
        (__attribute__((address_space(3))) u32*)l, 16, 0, 0);
}

// Fused prep (unchanged from r6 — measured fine):
//   [0, PB_BLOCKS)            : pb[n,m] = pos_enc[n,m,:].w + b
//   [.., +KCONV_BLOCKS)       : keys fp32 -> bf16, PRE-SWIZZLED slot order
//   [.., +ncopy)              : q/k/v pass-through copies
//   last                      : scale = sum(w)/sqrt(16)
__global__ void prep_kernel(const float* __restrict__ q, const float* __restrict__ k,
                            const float* __restrict__ v, const float* __restrict__ pos,
                            const float* __restrict__ w, const float* __restrict__ b,
                            float* __restrict__ pb, short* __restrict__ kbf,
                            float* __restrict__ scale_p,
                            float* __restrict__ qout, float* __restrict__ kout,
                            float* __restrict__ vout, int ncopy) {
    const int bid = blockIdx.x, tid = threadIdx.x;
    if (bid < PB_BLOCKS) {
        const int lane16 = tid & 15;
        const f32x4 w4 = ((const f32x4*)w)[lane16];
        const float bias = b[0];
        const int group = (bid * 256 + tid) >> 4;
        const int ngroups = (PB_BLOCKS * 256) >> 4;
        for (int pair = group; pair < N * M; pair += ngroups) {
            f32x4 p = __builtin_nontemporal_load((const f32x4*)pos + (size_t)pair * 16 + lane16);
            float s = p[0]*w4[0] + p[1]*w4[1] + p[2]*w4[2] + p[3]*w4[3];
            s += __shfl_xor(s, 1);
            s += __shfl_xor(s, 2);
            s += __shfl_xor(s, 4);
            s += __shfl_xor(s, 8);
            if (lane16 == 0) pb[pair] = s + bias;
        }
    } else if (bid < PB_BLOCKS + KCONV_BLOCKS) {
        const int cid = bid - PB_BLOCKS;
        const int total_slots = BH * N * 8;        // 16B slots, 1048576
        for (int gs = cid * 256 + tid; gs < total_slots; gs += KCONV_BLOCKS * 256) {
            const int qs = gs & 7, gr = (gs >> 3) & (N - 1), bb = gs >> 13;
            const float* src = k + ((size_t)bb * N + gr) * D + (qs ^ (gr & 7)) * 8;
            f32x4 x0 = ((const f32x4*)src)[0], x1 = ((const f32x4*)src)[1];
            short8 pk;
#pragma unroll
            for (int e = 0; e < 4; e++) { pk[e] = f2b(x0[e]); pk[4 + e] = f2b(x1[e]); }
            *(short8*)&kbf[(size_t)gs * 8] = pk;
        }
    } else if (bid < PB_BLOCKS + KCONV_BLOCKS + ncopy) {
        const int cid = bid - PB_BLOCKS - KCONV_BLOCKS;
        const int which = cid >> 8, lid = cid & 255;
        const f32x4* __restrict__ src = (which == 0) ? (const f32x4*)q
                                      : (which == 1) ? (const f32x4*)k : (const f32x4*)v;
        f32x4* __restrict__ dst = (which == 0) ? (f32x4*)qout
                                : (which == 1) ? (f32x4*)kout : (f32x4*)vout;
        const int nel4 = (int)(QKV_ELEMS / 4);
        for (int i = lid * 256 + tid; i < nel4; i += COPY_BLOCKS_PER * 256) {
            f32x4 x = __builtin_nontemporal_load(src + i);
            __builtin_nontemporal_store(x, dst + i);
        }
    } else {
        if (tid < 64) {
            float val = w[tid];
#pragma unroll
            for (int o = 32; o > 0; o >>= 1) val += __shfl_down(val, o);
            if (tid == 0) scale_p[0] = val * 0.25f;
        }
    }
}

// attn = (K K^T)*scale + pb.  2048 blocks, 32x256 tile, pf in registers,
// double-buffered batch staging with COUNTED vmcnt.  Race-fixed ordering:
// each wave waits for ITS OWN stage(t) loads (counted vmcnt) BEFORE the
// data-ready barrier; only then does any wave read the tile.  Stores are
// never drained to zero inside the loop.
__launch_bounds__(256)
__global__ void attn_kernel(const short* __restrict__ kbf, const float* __restrict__ pb,
                            const float* __restrict__ scale_p, float* __restrict__ out) {
    __shared__ short lK[2][(BR + BC) * 64];       // 2 x 36KB
    const int pos = blockIdx.x;                   // 0..127
    const int tr = pos >> 2, tc = pos & 3;        // 32 row-tiles x 4 col-tiles
    const int batch0 = blockIdx.y * BGROUP;
    const int tid = threadIdx.x;
    const float scale = scale_p[0];

    const int lane = tid & 63, wv = tid >> 6;     // 4 waves
    const int wr = wv >> 1, wc = wv & 1;          // 2x2: 16 rows x 128 cols each
    const int frow = lane & 15;
    const int kslot = lane >> 4;

    const int orow = tr * BR + wr * 16 + (lane >> 4) * 4;   // + r
    const int ocol = tc * BC + wc * 128 + (lane & 15);      // + j*16

    // pb fragments in accumulator layout — reused for all BGROUP batches.
    f32x4 pf[8];
#pragma unroll
    for (int j = 0; j < 8; j++)
#pragma unroll
        for (int r = 0; r < 4; r++)
            pf[j][r] = pb[(size_t)(orow + r) * M + (ocol + j * 16)];

    // Prologue: issue stage(0) into buf 0 (no wait here).
#pragma unroll
    for (int it = 0; it < 9; ++it) {
        const int slot = it * 256 + tid;
        const int row = slot >> 3, qs = slot & 7;
        const int gr = (row < BR) ? (tr * BR + row) : (tc * BC + (row - BR));
        gl_lds16(kbf + ((size_t)batch0 * N + gr) * 64 + qs * 8, &lK[0][slot * 8]);
    }

    for (int t = 0; t < BGROUP; ++t) {
        const int cur = t & 1;
        if (t + 1 < BGROUP) {
            // Issue next batch's stage into the other buffer (no wait).
            const short* __restrict__ Kn = kbf + (size_t)(batch0 + t + 1) * N * 64;
#pragma unroll
            for (int it = 0; it < 9; ++it) {
                const int slot = it * 256 + tid;
                const int row = slot >> 3, qs = slot & 7;
                const int gr = (row < BR) ? (tr * BR + row) : (tc * BC + (row - BR));
                gl_lds16(Kn + (size_t)gr * 64 + qs * 8, &lK[cur ^ 1][slot * 8]);
            }
        }
        // Drain OWN stage(t) loads (counted — older stores drain too, newer
        // stay in flight), THEN barrier: after it, every wave's slots are in.
        if (t == 0)                 asm volatile("s_waitcnt vmcnt(9)"  ::: "memory");
        else if (t + 1 < BGROUP)    asm volatile("s_waitcnt vmcnt(41)" ::: "memory");
        else                        asm volatile("s_waitcnt vmcnt(32)" ::: "memory");
        __builtin_amdgcn_s_barrier();
        asm volatile("" ::: "memory");            // no LDS access crosses above

        const int ra = wr * 16 + frow;
        short8 a0 = *(const short8*)&lK[cur][ra * 64 + ((kslot)     ^ (ra & 7)) * 8];
        short8 a1 = *(const short8*)&lK[cur][ra * 64 + ((4 + kslot) ^ (ra & 7)) * 8];

        f32x4 acc[8] = {};
#pragma unroll
        for (int j = 0; j < 8; ++j) {
            const int rb = BR + wc * 128 + j * 16 + frow;
            short8 b0 = *(const short8*)&lK[cur][rb * 64 + ((kslot)     ^ (rb & 7)) * 8];
            acc[j] = __builtin_amdgcn_mfma_f32_16x16x32_bf16(a0, b0, acc[j], 0, 0, 0);
        }
#pragma unroll
        for (int j = 0; j < 8; ++j) {
            const int rb = BR + wc * 128 + j * 16 + frow;
            short8 b1 = *(const short8*)&lK[cur][rb * 64 + ((4 + kslot) ^ (rb & 7)) * 8];
            acc[j] = __builtin_amdgcn_mfma_f32_16x16x32_bf16(a1, b1, acc[j], 0, 0, 0);
        }

        const size_t obase = (size_t)(batch0 + t) * N * M;
#pragma unroll
        for (int j = 0; j < 8; ++j)
#pragma unroll
            for (int r = 0; r < 4; ++r) {
                out[obase + (size_t)(orow + r) * M + (ocol + j * 16)]
                    = acc[j][r] * scale + pf[j][r];
            }

        if (t + 1 < BGROUP) {
            // All waves done READING lK[cur] before it's re-staged at t+1.
            // No vmcnt drain: stores keep flowing.
            asm volatile("s_waitcnt lgkmcnt(0)" ::: "memory");
            __builtin_amdgcn_s_barrier();
            asm volatile("" ::: "memory");
        }
    }
}

extern "C" void kernel_launch(void* const* d_in, const int* in_sizes, int n_in,
                              void* d_out, int out_size, void* d_ws, size_t ws_size,
                              hipStream_t stream) {
    const float* queries = (const float*)d_in[0];
    const float* keys    = (const float*)d_in[1];
    const float* values  = (const float*)d_in[2];
    const float* pos_enc = (const float*)d_in[3];
    const float* w_pos   = (const float*)d_in[4];
    const float* b_pos   = (const float*)d_in[5];

    float* out  = (float*)d_out;
    float* qout = out + ATTN_ELEMS;
    float* kout = qout + QKV_ELEMS;
    float* vout = kout + QKV_ELEMS;

    // ws layout: pb (N*M floats) | scale (16 floats) | kbf (BH*N*64 shorts)
    const size_t need_ws = ((size_t)N * M + 16) * sizeof(float)
                         + (size_t)BH * N * 64 * sizeof(short);
    const int npos = (N / BR) * (M / BC);         // 128 tile positions

    if (ws_size >= need_ws) {
        float* pb      = (float*)d_ws;
        float* scale_p = pb + (size_t)N * M;
        short* kbf     = (short*)(scale_p + 16);
        const int ncopy = 3 * COPY_BLOCKS_PER;
        prep_kernel<<<dim3(PB_BLOCKS + KCONV_BLOCKS + ncopy + 1), dim3(256), 0, stream>>>(
            queries, keys, values, pos_enc, w_pos, b_pos, pb, kbf, scale_p,
            qout, kout, vout, ncopy);
        attn_kernel<<<dim3(npos, BH / BGROUP), dim3(256), 0, stream>>>(kbf, pb, scale_p, out);
    } else {
        // Fallback: stash pb + scale + kbf in the q/k region of d_out (20MB),
        // run prep without copies, attn, then copy q/k/v after.
        float* pb      = qout;
        float* scale_p = pb + (size_t)N * M;
        short* kbf     = (short*)(scale_p + 16);
        prep_kernel<<<dim3(PB_BLOCKS + KCONV_BLOCKS + 1), dim3(256), 0, stream>>>(
            queries, keys, values, pos_enc, w_pos, b_pos, pb, kbf, scale_p,
            qout, kout, vout, /*ncopy=*/0);
        attn_kernel<<<dim3(npos, BH / BGROUP), dim3(256), 0, stream>>>(kbf, pb, scale_p, out);
        hipMemcpyAsync(qout, queries, QKV_ELEMS * sizeof(float), hipMemcpyDeviceToDevice, stream);
        hipMemcpyAsync(kout, keys,    QKV_ELEMS * sizeof(float), hipMemcpyDeviceToDevice, stream);
        hipMemcpyAsync(vout, values,  QKV_ELEMS * sizeof(float), hipMemcpyDeviceToDevice, stream);
    }
}